// Round 7
// baseline (565.929 us; speedup 1.0000x reference)
//
#include <hip/hip_runtime.h>

#define S_LEN  2048
#define BATCH  2
#define DMODEL 1024
#define NHEADS 16
#define DHEAD  64
#define DFF    4096
#define MROWS  (S_LEN*BATCH)   // 4096
#define QKVN   3072

typedef __attribute__((ext_vector_type(8))) short bf16x8;
typedef __attribute__((ext_vector_type(4))) float f32x4;
typedef __attribute__((ext_vector_type(4))) short s16x4;

#define NEG_BIG (-3.0e38f)
#define SCALE_LOG2 (0.125f * 1.4426950408889634f)

__device__ __forceinline__ short f2bf(float f){
  unsigned u = __float_as_uint(f);
  u += 0x7fffu + ((u >> 16) & 1u);
  return (short)(u >> 16);
}

__device__ __forceinline__ void gload16(const void* gptr, void* lptr){
  __builtin_amdgcn_global_load_lds(
      (const __attribute__((address_space(1))) unsigned int*)gptr,
      (__attribute__((address_space(3))) unsigned int*)lptr,
      16, 0, 0);
}

// ---------------- cast f32 -> bf16 ----------------
__global__ __launch_bounds__(256) void cast_kernel(const float* __restrict__ in,
                                                   short* __restrict__ out, int n){
  int i = (blockIdx.x * 256 + threadIdx.x) * 4;
  if (i >= n) return;
  f32x4 v = *(const f32x4*)(in + i);
  s16x4 o;
  o[0] = f2bf(v[0]); o[1] = f2bf(v[1]); o[2] = f2bf(v[2]); o[3] = f2bf(v[3]);
  *(s16x4*)(out + i) = o;
}

// ---------------- fused cast + KL: out=bf16(mean); acc += KL(mean,std) ------
__global__ __launch_bounds__(256) void cast_kl_kernel(const float* __restrict__ mean,
                                                      const float* __restrict__ stdv,
                                                      short* __restrict__ outb,
                                                      int n, double* acc){
  __shared__ double red[4];
  double local = 0.0;
  const int stride = gridDim.x * 1024;
  for (int i = (blockIdx.x * 256 + threadIdx.x) * 4; i < n; i += stride){
    f32x4 m = *(const f32x4*)(mean + i);
    f32x4 sv = *(const f32x4*)(stdv + i);
    if (outb){
      s16x4 o;
      o[0] = f2bf(m[0]); o[1] = f2bf(m[1]); o[2] = f2bf(m[2]); o[3] = f2bf(m[3]);
      *(s16x4*)(outb + i) = o;
    }
    for (int e = 0; e < 4; e++)
      local += (double)(m[e] * m[e]) - 2.0 * (double)sv[e] + (double)expf(2.f * sv[e]);
  }
  for (int msk = 1; msk < 64; msk <<= 1) local += __shfl_xor(local, msk, 64);
  const int t = threadIdx.x;
  if ((t & 63) == 0) red[t >> 6] = local;
  __syncthreads();
  if (t == 0) atomicAdd(acc, red[0] + red[1] + red[2] + red[3]);
}

__global__ void kl_final(const double* acc, float* out){
  out[0] = (float)(acc[0] / 8388608.0 + acc[1] / 16777216.0);
}

// ---------------- GEMM: C[M][N] = A[M][K] * Bt[N][K]^T ----------------
// 128xBN tile, BK=32, 8 waves, global_load_lds w=16, QUAD-buffered LDS,
// prefetch depth 3, counted vmcnt (T4: never drain to 0 in main loop),
// one barrier per K-step. 1D grid, chunked XCD swizzle (nwg % 8 == 0).
template<int BN>
__global__ __launch_bounds__(512) void gemm_bt(const short* __restrict__ A,
                                               const short* __restrict__ Bt,
                                               float* __restrict__ Cf,
                                               short* __restrict__ Cb,
                                               int M, int N, int K, int nbx){
  __shared__ short As[4][128][32];
  __shared__ short Bs[4][BN][32];
  constexpr int NB = BN / 32;          // n-frags per wave
  constexpr int BSTRIDE = BN * 64;     // bytes per B buffer
  const int t = threadIdx.x;
  const int lane = t & 63, w = t >> 6;
  const int q8 = (int)gridDim.x >> 3;
  const int sid = ((int)blockIdx.x & 7) * q8 + ((int)blockIdx.x >> 3);
  const int bx = sid % nbx, by = sid / nbx;
  const int m0 = by * 128, n0 = bx * BN;
  const int wm = (w & 3) * 32, wn = (w >> 2) * (BN / 2);
  const int lr = lane & 15, lg = lane >> 4;
  const bool doB = (BN == 128) || (t < 256);
  const bool twoLoads = (BN == 128) || (w < 4);

  f32x4 acc[2][NB] = {};

  const short* Ap = A  + (size_t)(m0 + (t >> 2)) * K + (t & 3) * 8;
  const short* Bp = Bt + (size_t)(n0 + ((t & (BN * 4 - 1)) >> 2)) * K + (t & 3) * 8;
  char* ldsA0 = (char*)As + w * 1024;
  char* ldsB0 = (char*)Bs + (w & (NB * 2 - 1)) * 1024;

  const int nk = K / 32;
  // prologue: stage tiles 0,1,2 into bufs 0,1,2
  for (int p = 0; p < 3; p++){
    gload16(Ap + p * 32, ldsA0 + p * 8192);
    if (doB) gload16(Bp + p * 32, ldsB0 + p * BSTRIDE);
  }

  for (int kt = 0; kt < nk; kt++){
    const int rem = nk - 1 - kt;  // future tiles still prefetched
    if (twoLoads){
      if (rem >= 2)      asm volatile("s_waitcnt vmcnt(4)" ::: "memory");
      else if (rem == 1) asm volatile("s_waitcnt vmcnt(2)" ::: "memory");
      else               asm volatile("s_waitcnt vmcnt(0)" ::: "memory");
    } else {
      if (rem >= 2)      asm volatile("s_waitcnt vmcnt(2)" ::: "memory");
      else if (rem == 1) asm volatile("s_waitcnt vmcnt(1)" ::: "memory");
      else               asm volatile("s_waitcnt vmcnt(0)" ::: "memory");
    }
    __builtin_amdgcn_s_barrier();
    asm volatile("" ::: "memory");

    // issue next prefetch FIRST (T3: stage before ds_read+MFMA)
    const int nxt = kt + 3;
    if (nxt < nk){
      gload16(Ap + nxt * 32, ldsA0 + (nxt & 3) * 8192);
      if (doB) gload16(Bp + nxt * 32, ldsB0 + (nxt & 3) * BSTRIDE);
    }

    const int cur = kt & 3;
    bf16x8 a0 = *(const bf16x8*)&As[cur][wm      + lr][lg * 8];
    bf16x8 a1 = *(const bf16x8*)&As[cur][wm + 16 + lr][lg * 8];
    bf16x8 bfr[NB];
    for (int ni = 0; ni < NB; ni++)
      bfr[ni] = *(const bf16x8*)&Bs[cur][wn + ni * 16 + lr][lg * 8];
    __builtin_amdgcn_s_setprio(1);
    for (int ni = 0; ni < NB; ni++){
      acc[0][ni] = __builtin_amdgcn_mfma_f32_16x16x32_bf16(a0, bfr[ni], acc[0][ni], 0, 0, 0);
      acc[1][ni] = __builtin_amdgcn_mfma_f32_16x16x32_bf16(a1, bfr[ni], acc[1][ni], 0, 0, 0);
    }
    __builtin_amdgcn_s_setprio(0);
  }

  for (int mi = 0; mi < 2; mi++){
    for (int ni = 0; ni < NB; ni++){
      int row = m0 + wm + mi * 16 + lg * 4;
      int col = n0 + wn + ni * 16 + lr;
      for (int r = 0; r < 4; r++){
        float v = acc[mi][ni][r];
        if (Cf) Cf[(size_t)(row + r) * N + col] = v;
        if (Cb) Cb[(size_t)(row + r) * N + col] = f2bf(v);
      }
    }
  }
}

// ---------------- fused causal flash attention (swapped-QK^T) ----------------
// grid (32, B*NH): one q-tile per block, long blocks (qt=31) dispatched first.
// block 256 (4 waves x 16 q-rows). mfma(K,Q) => S[j][q=lr]: softmax is
// thread-local per q-row; defer-max (THR=8, log2 domain); scale folded in fmaf.
__global__ __launch_bounds__(256) void attn_kernel(const short* __restrict__ QKV,
                                                   short* __restrict__ AV){
  __shared__ short Ks[64][64];
  __shared__ short Vst[64][64];   // transposed: [dh][j], swizzled
  __shared__ short Pt[4][16][64]; // per-wave P^T: [q(lr)][j], swizzled
  const int t = threadIdx.x, lane = t & 63, w = t >> 6;
  const int hb = blockIdx.y;
  const int b = hb >> 4, n = hb & 15;
  const int lr = lane & 15, lg = lane >> 4;

  const int qt = 31 - (int)blockIdx.x;
  const int q0w = qt * 64 + w * 16;

  // Q fragments: b-operand rows q = q0w + lr, k = kk*32 + lg*8 + i
  bf16x8 aq[2];
  {
    const short* qp = QKV + ((size_t)(q0w + lr) * BATCH + b) * QKVN + n * DHEAD + lg * 8;
    aq[0] = *(const bf16x8*)(qp);
    aq[1] = *(const bf16x8*)(qp + 32);
  }

  f32x4 acc[4] = {};
  float m_run = NEG_BIG, l_run = 0.f;

  for (int jt = 0; jt <= qt; jt++){
    const int j0 = jt * 64;
    __syncthreads();
    {
      // stage K tile [64 j][64 d], swizzled units
      int j = t >> 2, u0 = (t & 3) * 2;
      const short* kp = QKV + ((size_t)(j0 + j) * BATCH + b) * QKVN + DMODEL + n * DHEAD + u0 * 8;
      *(bf16x8*)&Ks[j][(u0 ^ (j & 7)) * 8]       = *(const bf16x8*)(kp);
      *(bf16x8*)&Ks[j][((u0 + 1) ^ (j & 7)) * 8] = *(const bf16x8*)(kp + 8);
      // stage V transposed [64 dh][64 j], swizzled
      int jv = t & 63, dq = (t >> 6) * 16;
      const short* vp = QKV + ((size_t)(j0 + jv) * BATCH + b) * QKVN + 2 * DMODEL + n * DHEAD + dq;
      bf16x8 v0 = *(const bf16x8*)(vp);
      bf16x8 v1 = *(const bf16x8*)(vp + 8);
      int uj = jv >> 3, jl = jv & 7;
      for (int e = 0; e < 8; e++){
        int sc = (((uj ^ e) << 3) | jl);
        Vst[dq + e][sc]     = v0[e];
        Vst[dq + 8 + e][sc] = v1[e];
      }
    }
    __syncthreads();

    // scores (swapped, RAW): s[nf] = S[j0 + nf*16 + lg*4 + r][q = q0w + lr]
    f32x4 s[4];
    __builtin_amdgcn_s_setprio(1);
    for (int nf = 0; nf < 4; nf++){
      f32x4 z = {};
      for (int kk = 0; kk < 2; kk++){
        bf16x8 bk = *(const bf16x8*)&Ks[nf * 16 + lr][((kk * 4 + lg) ^ (lr & 7)) * 8];
        z = __builtin_amdgcn_mfma_f32_16x16x32_bf16(bk, aq[kk], z, 0, 0, 0);
      }
      s[nf] = z;
    }
    __builtin_amdgcn_s_setprio(0);

    if (jt == qt){   // wave-uniform: mask only the diagonal tile (raw domain)
      int qg = q0w + lr;
      for (int nf = 0; nf < 4; nf++)
        for (int r = 0; r < 4; r++)
          if (j0 + nf * 16 + lg * 4 + r > qg) s[nf][r] = NEG_BIG;
    }

    // raw row max (scale is positive => monotone), then 1 mul to scaled domain
    float mx = NEG_BIG;
    for (int nf = 0; nf < 4; nf++){
      float a0 = fmaxf(s[nf][0], s[nf][1]);
      float a1 = fmaxf(s[nf][2], s[nf][3]);
      mx = fmaxf(mx, fmaxf(a0, a1));
    }
    mx = fmaxf(mx, __shfl_xor(mx, 16, 64));
    mx = fmaxf(mx, __shfl_xor(mx, 32, 64));
    float mxs = mx * SCALE_LOG2;

    // defer-max (T13): rescale only when some row grew past THR=8 (log2)
    if (__any(mxs > m_run + 8.f)){
      float mn = fmaxf(m_run, mxs);
      float corr = __builtin_exp2f(m_run - mn);
      m_run = mn;
      l_run *= corr;
      float cb[4];
      for (int r = 0; r < 4; r++) cb[r] = __shfl(corr, lg * 4 + r, 64);
      for (int df = 0; df < 4; df++)
        for (int r = 0; r < 4; r++) acc[df][r] *= cb[r];
    }

    // P = exp2(fma(s, SCALE, -m)) + row sum
    float rs = 0.f;
    for (int nf = 0; nf < 4; nf++)
      for (int r = 0; r < 4; r++){
        float p = __builtin_exp2f(fmaf(s[nf][r], SCALE_LOG2, -m_run));
        s[nf][r] = p;
        rs += p;
      }
    rs += __shfl_xor(rs, 16, 64);
    rs += __shfl_xor(rs, 32, 64);
    l_run += rs;

    // pack P (truncate to bf16) -> swizzled Pt row q=lr, b64 writes
    char* prow = (char*)&Pt[w][lr][0];
    for (int nf = 0; nf < 4; nf++){
      unsigned u0 = __float_as_uint(s[nf][0]);
      unsigned u1 = __float_as_uint(s[nf][1]);
      unsigned u2 = __float_as_uint(s[nf][2]);
      unsigned u3 = __float_as_uint(s[nf][3]);
      uint2 val;
      val.x = (u0 >> 16) | (u1 & 0xffff0000u);
      val.y = (u2 >> 16) | (u3 & 0xffff0000u);
      int off = ((((nf * 2) + (lg >> 1)) ^ (lr & 7)) << 4) + ((lg & 1) << 3);
      *(uint2*)(prow + off) = val;
    }

    // PV: acc[df] += P(16q x 64j) * V(64j x 16dh)
    __builtin_amdgcn_s_setprio(1);
    for (int kk = 0; kk < 2; kk++){
      bf16x8 pa = *(const bf16x8*)(prow + ((((kk * 4) + lg) ^ (lr & 7)) << 4));
      for (int df = 0; df < 4; df++){
        bf16x8 bv = *(const bf16x8*)&Vst[df * 16 + lr][((kk * 4 + lg) ^ (lr & 7)) * 8];
        acc[df] = __builtin_amdgcn_mfma_f32_16x16x32_bf16(pa, bv, acc[df], 0, 0, 0);
      }
    }
    __builtin_amdgcn_s_setprio(0);
  }

  // epilogue: divide by l (broadcast to acc-row owners), write attn_vec
  float lb[4];
  for (int r = 0; r < 4; r++) lb[r] = __shfl(l_run, lg * 4 + r, 64);
  for (int df = 0; df < 4; df++){
    for (int r = 0; r < 4; r++){
      int i_glob = q0w + lg * 4 + r;
      AV[((size_t)i_glob * BATCH + b) * DMODEL + n * DHEAD + df * 16 + lr] =
          f2bf(acc[df][r] / lb[r]);
    }
  }
}

// ---------------- LayerNorm: out = g*(xa+xb - mu)*rstd + b ----------------
__global__ __launch_bounds__(256) void ln_kernel(const float* __restrict__ xa,
                                                 const float* __restrict__ xb,
                                                 const float* __restrict__ gamma,
                                                 const float* __restrict__ beta,
                                                 float* __restrict__ outF,
                                                 short* __restrict__ outB){
  __shared__ float red[4];
  const int row = blockIdx.x, t = threadIdx.x;
  const size_t base = (size_t)row * DMODEL + t * 4;
  f32x4 a  = *(const f32x4*)(xa + base);
  f32x4 bb = *(const f32x4*)(xb + base);
  f32x4 x;
  for (int e = 0; e < 4; e++) x[e] = a[e] + bb[e];
  float sum = x[0] + x[1] + x[2] + x[3];
  for (int m = 1; m < 64; m <<= 1) sum += __shfl_xor(sum, m, 64);
  if ((t & 63) == 0) red[t >> 6] = sum;
  __syncthreads();
  float mu = (red[0] + red[1] + red[2] + red[3]) * (1.f / DMODEL);
  float sq = 0.f;
  for (int e = 0; e < 4; e++){ float d = x[e] - mu; sq += d * d; }
  for (int m = 1; m < 64; m <<= 1) sq += __shfl_xor(sq, m, 64);
  __syncthreads();
  if ((t & 63) == 0) red[t >> 6] = sq;
  __syncthreads();
  float var = (red[0] + red[1] + red[2] + red[3]) * (1.f / DMODEL);
  float rstd = rsqrtf(var + 1e-5f);
  f32x4 g  = *(const f32x4*)(gamma + t * 4);
  f32x4 be = *(const f32x4*)(beta + t * 4);
  for (int e = 0; e < 4; e++){
    float y = g[e] * (x[e] - mu) * rstd + be[e];
    if (outF) outF[base + e] = y;
    if (outB) outB[base + e] = f2bf(y);
  }
}

// ---------------- launch ----------------
extern "C" void kernel_launch(void* const* d_in, const int* in_sizes, int n_in,
                              void* d_out, int out_size, void* d_ws, size_t ws_size,
                              hipStream_t stream){
  (void)in_sizes; (void)n_in; (void)out_size; (void)ws_size;
  const float* dec = (const float*)d_in[0];
  const float* qm  = (const float*)d_in[2];
  const float* km  = (const float*)d_in[3];
  const float* vm  = (const float*)d_in[4];
  const float* qs  = (const float*)d_in[5];
  const float* ks  = (const float*)d_in[6];
  const float* vs  = (const float*)d_in[7];
  const float* om  = (const float*)d_in[8];
  const float* os_ = (const float*)d_in[9];
  const float* g1  = (const float*)d_in[10];
  const float* b1  = (const float*)d_in[11];
  const float* w1m = (const float*)d_in[12];
  const float* w2m = (const float*)d_in[13];
  const float* w1s = (const float*)d_in[14];
  const float* w2s = (const float*)d_in[15];
  const float* g2  = (const float*)d_in[16];
  const float* b2  = (const float*)d_in[17];
  float* out = (float*)d_out;

  char* ws = (char*)d_ws;
  size_t off = 0;
  auto alloc = [&](size_t bytes) -> char* {
    char* p = ws + off;
    off += (bytes + 255) & ~(size_t)255;
    return p;
  };
  short* Xb   = (short*)alloc((size_t)MROWS * DMODEL * 2);   // X bf16; then h bf16
  short* Wqkv = (short*)alloc((size_t)QKVN * DMODEL * 2);    // [3072][1024]
  short* W1   = (short*)alloc((size_t)DFF * DMODEL * 2);
  short* W2   = (short*)alloc((size_t)DMODEL * DFF * 2);
  short* Wv   = Wqkv + (size_t)2 * DMODEL * DMODEL;          // V weights within Wqkv
  short* QKVb = (short*)alloc((size_t)MROWS * QKVN * 2);     // [4096][3072], 24MB
  short* AVb  = (short*)alloc((size_t)MROWS * DMODEL * 2);   // 8MB, contiguous after QKVb
  float* tmpF = (float*)alloc((size_t)MROWS * DMODEL * 4);
  float* hF   = (float*)alloc((size_t)MROWS * DMODEL * 4);
  double* acc = (double*)alloc(256);
  short* L1 = QKVb;  // reuse QKVb+AVb region (32MB) for l1 [4096][4096] bf16

  hipMemsetAsync(acc, 0, 16, stream);

  // casts (+ fused KL on the weight tensors)
  cast_kernel<<<MROWS * DMODEL / 1024, 256, 0, stream>>>(dec, Xb, MROWS * DMODEL);
  cast_kl_kernel<<<1024, 256, 0, stream>>>(qm, qs, Wqkv, DMODEL * DMODEL, acc);
  cast_kl_kernel<<<1024, 256, 0, stream>>>(km, ks, Wqkv + (size_t)DMODEL * DMODEL, DMODEL * DMODEL, acc);
  cast_kl_kernel<<<1024, 256, 0, stream>>>(vm, vs, Wqkv + (size_t)2 * DMODEL * DMODEL, DMODEL * DMODEL, acc);
  cast_kl_kernel<<<1024, 256, 0, stream>>>(om, os_, nullptr, DMODEL * DMODEL, acc);
  cast_kl_kernel<<<1024, 256, 0, stream>>>(w1m, w1s, W1, DFF * DMODEL, acc + 1);
  cast_kl_kernel<<<1024, 256, 0, stream>>>(w2m, w2s, W2, DMODEL * DFF, acc + 1);

  // fused QKV projection: [4096][3072] = Xb[4096][1024] @ Wqkv^T
  gemm_bt<128><<<(QKVN / 128) * (MROWS / 128), 512, 0, stream>>>(Xb, Wqkv, nullptr, QKVb, MROWS, QKVN, DMODEL, QKVN / 128);

  // attention (one q-tile per block, long blocks first)
  attn_kernel<<<dim3(32, BATCH * NHEADS), 256, 0, stream>>>(QKVb, AVb);

  // attn output projection (bug-faithful: uses value_mean); BN=64 -> 512 blocks
  gemm_bt<64><<<(DMODEL / 64) * (MROWS / 128), 512, 0, stream>>>(AVb, Wv, tmpF, nullptr, MROWS, DMODEL, DMODEL, DMODEL / 64);

  // LN1: h = LN(dec + attn_out) -> hF (f32) + Xb (bf16)
  ln_kernel<<<MROWS, 256, 0, stream>>>(dec, tmpF, g1, b1, hF, Xb);

  // FF
  gemm_bt<128><<<(DFF / 128) * (MROWS / 128), 512, 0, stream>>>(Xb, W1, nullptr, L1, MROWS, DFF, DMODEL, DFF / 128);
  gemm_bt<64><<<(DMODEL / 64) * (MROWS / 128), 512, 0, stream>>>(L1, W2, tmpF, nullptr, MROWS, DMODEL, DFF, DMODEL / 64);

  // LN2 -> final out
  ln_kernel<<<MROWS, 256, 0, stream>>>(hF, tmpF, g2, b2, out, nullptr);

  // KL finalize
  kl_final<<<1, 1, 0, stream>>>(acc, out + (size_t)MROWS * DMODEL);
}

// Round 8
// 535.333 us; speedup vs baseline: 1.0572x; 1.0572x over previous
//
#include <hip/hip_runtime.h>

#define S_LEN  2048
#define BATCH  2
#define DMODEL 1024
#define NHEADS 16
#define DHEAD  64
#define DFF    4096
#define MROWS  (S_LEN*BATCH)   // 4096
#define QKVN   3072

typedef __attribute__((ext_vector_type(8))) short bf16x8;
typedef __attribute__((ext_vector_type(4))) float f32x4;
typedef __attribute__((ext_vector_type(4))) short s16x4;

#define NEG_BIG (-3.0e38f)
#define SCALE_LOG2 (0.125f * 1.4426950408889634f)

__device__ __forceinline__ short f2bf(float f){
  unsigned u = __float_as_uint(f);
  u += 0x7fffu + ((u >> 16) & 1u);
  return (short)(u >> 16);
}

__device__ __forceinline__ void gload16(const void* gptr, void* lptr){
  __builtin_amdgcn_global_load_lds(
      (const __attribute__((address_space(1))) unsigned int*)gptr,
      (__attribute__((address_space(3))) unsigned int*)lptr,
      16, 0, 0);
}

// ---------------- cast f32 -> bf16 ----------------
__global__ __launch_bounds__(256) void cast_kernel(const float* __restrict__ in,
                                                   short* __restrict__ out, int n){
  int i = (blockIdx.x * 256 + threadIdx.x) * 4;
  if (i >= n) return;
  f32x4 v = *(const f32x4*)(in + i);
  s16x4 o;
  o[0] = f2bf(v[0]); o[1] = f2bf(v[1]); o[2] = f2bf(v[2]); o[3] = f2bf(v[3]);
  *(s16x4*)(out + i) = o;
}

// ---------------- fused cast + KL: out=bf16(mean); acc += KL(mean,std) ------
__global__ __launch_bounds__(256) void cast_kl_kernel(const float* __restrict__ mean,
                                                      const float* __restrict__ stdv,
                                                      short* __restrict__ outb,
                                                      int n, double* acc){
  __shared__ double red[4];
  double local = 0.0;
  const int stride = gridDim.x * 1024;
  for (int i = (blockIdx.x * 256 + threadIdx.x) * 4; i < n; i += stride){
    f32x4 m = *(const f32x4*)(mean + i);
    f32x4 sv = *(const f32x4*)(stdv + i);
    if (outb){
      s16x4 o;
      o[0] = f2bf(m[0]); o[1] = f2bf(m[1]); o[2] = f2bf(m[2]); o[3] = f2bf(m[3]);
      *(s16x4*)(outb + i) = o;
    }
    for (int e = 0; e < 4; e++)
      local += (double)(m[e] * m[e]) - 2.0 * (double)sv[e] + (double)expf(2.f * sv[e]);
  }
  for (int msk = 1; msk < 64; msk <<= 1) local += __shfl_xor(local, msk, 64);
  const int t = threadIdx.x;
  if ((t & 63) == 0) red[t >> 6] = local;
  __syncthreads();
  if (t == 0) atomicAdd(acc, red[0] + red[1] + red[2] + red[3]);
}

__global__ void kl_final(const double* acc, float* out){
  out[0] = (float)(acc[0] / 8388608.0 + acc[1] / 16777216.0);
}

// ---------------- GEMM: C[M][N] = A[M][K] * Bt[N][K]^T ----------------
// 128xBN tile, BK=32, 8 waves, global_load_lds w=16, TRIPLE-buffered LDS,
// prefetch depth 2, counted vmcnt (never 0 mid-loop), one barrier/K-step.
// LDS: BN=128 -> 48 KB (3 blk/CU); BN=64 -> 36 KB (4 blk/CU).
template<int BN>
__global__ __launch_bounds__(512) void gemm_bt(const short* __restrict__ A,
                                               const short* __restrict__ Bt,
                                               float* __restrict__ Cf,
                                               short* __restrict__ Cb,
                                               int M, int N, int K, int nbx){
  __shared__ short As[3][128][32];
  __shared__ short Bs[3][BN][32];
  constexpr int NB = BN / 32;          // n-frags per wave
  constexpr int BSTRIDE = BN * 64;     // bytes per B buffer
  const int t = threadIdx.x;
  const int lane = t & 63, w = t >> 6;
  const int q8 = (int)gridDim.x >> 3;
  const int sid = ((int)blockIdx.x & 7) * q8 + ((int)blockIdx.x >> 3);
  const int bx = sid % nbx, by = sid / nbx;
  const int m0 = by * 128, n0 = bx * BN;
  const int wm = (w & 3) * 32, wn = (w >> 2) * (BN / 2);
  const int lr = lane & 15, lg = lane >> 4;
  const bool doB = (BN == 128) || (t < 256);

  f32x4 acc[2][NB] = {};

  const short* Ap = A  + (size_t)(m0 + (t >> 2)) * K + (t & 3) * 8;
  const short* Bp = Bt + (size_t)(n0 + ((t & (BN * 4 - 1)) >> 2)) * K + (t & 3) * 8;
  char* ldsA0 = (char*)As + w * 1024;
  char* ldsB0 = (char*)Bs + (w & (NB * 2 - 1)) * 1024;

  const int nk = K / 32;
  // prologue: stage tiles 0,1 into bufs 0,1 (depth-2)
  for (int p = 0; p < 2; p++){
    gload16(Ap + p * 32, ldsA0 + p * 8192);
    if (doB) gload16(Bp + p * 32, ldsB0 + p * BSTRIDE);
  }

  int bufcur = 0;
  for (int kt = 0; kt < nk; kt++){
    // wait for tile kt's loads; leave tile kt+1's in flight (counted vmcnt)
    if (kt + 1 < nk){
      if (doB) asm volatile("s_waitcnt vmcnt(2)" ::: "memory");
      else     asm volatile("s_waitcnt vmcnt(1)" ::: "memory");
    } else {
      asm volatile("s_waitcnt vmcnt(0)" ::: "memory");
    }
    __builtin_amdgcn_s_barrier();
    asm volatile("" ::: "memory");

    // issue tile kt+2 into the buffer freed at iter kt-1
    if (kt + 2 < nk){
      int bnx = bufcur >= 1 ? bufcur - 1 : bufcur + 2;  // (kt+2)%3
      gload16(Ap + (kt + 2) * 32, ldsA0 + bnx * 8192);
      if (doB) gload16(Bp + (kt + 2) * 32, ldsB0 + bnx * BSTRIDE);
    }

    bf16x8 a0 = *(const bf16x8*)&As[bufcur][wm      + lr][lg * 8];
    bf16x8 a1 = *(const bf16x8*)&As[bufcur][wm + 16 + lr][lg * 8];
    bf16x8 bfr[NB];
    for (int ni = 0; ni < NB; ni++)
      bfr[ni] = *(const bf16x8*)&Bs[bufcur][wn + ni * 16 + lr][lg * 8];
    __builtin_amdgcn_s_setprio(1);
    for (int ni = 0; ni < NB; ni++){
      acc[0][ni] = __builtin_amdgcn_mfma_f32_16x16x32_bf16(a0, bfr[ni], acc[0][ni], 0, 0, 0);
      acc[1][ni] = __builtin_amdgcn_mfma_f32_16x16x32_bf16(a1, bfr[ni], acc[1][ni], 0, 0, 0);
    }
    __builtin_amdgcn_s_setprio(0);
    bufcur = bufcur < 2 ? bufcur + 1 : 0;
  }

  for (int mi = 0; mi < 2; mi++){
    for (int ni = 0; ni < NB; ni++){
      int row = m0 + wm + mi * 16 + lg * 4;
      int col = n0 + wn + ni * 16 + lr;
      for (int r = 0; r < 4; r++){
        float v = acc[mi][ni][r];
        if (Cf) Cf[(size_t)(row + r) * N + col] = v;
        if (Cb) Cb[(size_t)(row + r) * N + col] = f2bf(v);
      }
    }
  }
}

// ---------------- fused causal flash attention (swapped-QK^T) ----------------
// grid (16, B*NH): each block does q-tiles bx and 31-bx (uniform 33 K-tiles,
// balanced makespan — r7's one-tile-per-block skewed per-CU work 4..128 units).
// block 256 (4 waves x 16 q-rows). mfma(K,Q) => S[j][q=lr]: softmax is
// thread-local per q-row; defer-max (THR=8, log2); scale folded into exp2 fma.
__global__ __launch_bounds__(256) void attn_kernel(const short* __restrict__ QKV,
                                                   short* __restrict__ AV){
  __shared__ short Ks[64][64];
  __shared__ short Vst[64][64];   // transposed: [dh][j], swizzled
  __shared__ short Pt[4][16][64]; // per-wave P^T: [q(lr)][j], swizzled
  const int t = threadIdx.x, lane = t & 63, w = t >> 6;
  const int hb = blockIdx.y;
  const int b = hb >> 4, n = hb & 15;
  const int lr = lane & 15, lg = lane >> 4;

  for (int half = 0; half < 2; half++){
    const int qt = half ? (31 - (int)blockIdx.x) : (int)blockIdx.x;
    const int q0w = qt * 64 + w * 16;

    // Q fragments: b-operand rows q = q0w + lr, k = kk*32 + lg*8 + i
    bf16x8 aq[2];
    {
      const short* qp = QKV + ((size_t)(q0w + lr) * BATCH + b) * QKVN + n * DHEAD + lg * 8;
      aq[0] = *(const bf16x8*)(qp);
      aq[1] = *(const bf16x8*)(qp + 32);
    }

    f32x4 acc[4] = {};
    float m_run = NEG_BIG, l_run = 0.f;

    for (int jt = 0; jt <= qt; jt++){
      const int j0 = jt * 64;
      __syncthreads();
      {
        // stage K tile [64 j][64 d], swizzled units
        int j = t >> 2, u0 = (t & 3) * 2;
        const short* kp = QKV + ((size_t)(j0 + j) * BATCH + b) * QKVN + DMODEL + n * DHEAD + u0 * 8;
        *(bf16x8*)&Ks[j][(u0 ^ (j & 7)) * 8]       = *(const bf16x8*)(kp);
        *(bf16x8*)&Ks[j][((u0 + 1) ^ (j & 7)) * 8] = *(const bf16x8*)(kp + 8);
        // stage V transposed [64 dh][64 j], swizzled
        int jv = t & 63, dq = (t >> 6) * 16;
        const short* vp = QKV + ((size_t)(j0 + jv) * BATCH + b) * QKVN + 2 * DMODEL + n * DHEAD + dq;
        bf16x8 v0 = *(const bf16x8*)(vp);
        bf16x8 v1 = *(const bf16x8*)(vp + 8);
        int uj = jv >> 3, jl = jv & 7;
        for (int e = 0; e < 8; e++){
          int sc = (((uj ^ e) << 3) | jl);
          Vst[dq + e][sc]     = v0[e];
          Vst[dq + 8 + e][sc] = v1[e];
        }
      }
      __syncthreads();

      // scores (swapped, raw): s[nf] = S[j0 + nf*16 + lg*4 + r][q = q0w + lr]
      f32x4 s[4];
      __builtin_amdgcn_s_setprio(1);
      for (int nf = 0; nf < 4; nf++){
        f32x4 z = {};
        for (int kk = 0; kk < 2; kk++){
          bf16x8 bk = *(const bf16x8*)&Ks[nf * 16 + lr][((kk * 4 + lg) ^ (lr & 7)) * 8];
          z = __builtin_amdgcn_mfma_f32_16x16x32_bf16(bk, aq[kk], z, 0, 0, 0);
        }
        s[nf] = z;
      }
      __builtin_amdgcn_s_setprio(0);

      if (jt == qt){   // wave-uniform: mask only the diagonal tile (raw domain)
        int qg = q0w + lr;
        for (int nf = 0; nf < 4; nf++)
          for (int r = 0; r < 4; r++)
            if (j0 + nf * 16 + lg * 4 + r > qg) s[nf][r] = NEG_BIG;
      }

      // raw row max (positive scale => monotone), 16 local + 2 shfl
      float mx = NEG_BIG;
      for (int nf = 0; nf < 4; nf++){
        float a0 = fmaxf(s[nf][0], s[nf][1]);
        float a1 = fmaxf(s[nf][2], s[nf][3]);
        mx = fmaxf(mx, fmaxf(a0, a1));
      }
      mx = fmaxf(mx, __shfl_xor(mx, 16, 64));
      mx = fmaxf(mx, __shfl_xor(mx, 32, 64));
      float mxs = mx * SCALE_LOG2;

      // defer-max (T13): rescale only when some row grew past THR=8 (log2)
      if (__any(mxs > m_run + 8.f)){
        float mn = fmaxf(m_run, mxs);
        float corr = __builtin_exp2f(m_run - mn);
        m_run = mn;
        l_run *= corr;
        float cb[4];
        for (int r = 0; r < 4; r++) cb[r] = __shfl(corr, lg * 4 + r, 64);
        for (int df = 0; df < 4; df++)
          for (int r = 0; r < 4; r++) acc[df][r] *= cb[r];
      }

      // P = exp2(fma(s, SCALE, -m)) + row sum
      float rs = 0.f;
      for (int nf = 0; nf < 4; nf++)
        for (int r = 0; r < 4; r++){
          float p = __builtin_exp2f(fmaf(s[nf][r], SCALE_LOG2, -m_run));
          s[nf][r] = p;
          rs += p;
        }
      rs += __shfl_xor(rs, 16, 64);
      rs += __shfl_xor(rs, 32, 64);
      l_run += rs;

      // pack P (truncate to bf16) -> swizzled Pt row q=lr, b64 writes
      char* prow = (char*)&Pt[w][lr][0];
      for (int nf = 0; nf < 4; nf++){
        unsigned u0 = __float_as_uint(s[nf][0]);
        unsigned u1 = __float_as_uint(s[nf][1]);
        unsigned u2 = __float_as_uint(s[nf][2]);
        unsigned u3 = __float_as_uint(s[nf][3]);
        uint2 val;
        val.x = (u0 >> 16) | (u1 & 0xffff0000u);
        val.y = (u2 >> 16) | (u3 & 0xffff0000u);
        int off = ((((nf * 2) + (lg >> 1)) ^ (lr & 7)) << 4) + ((lg & 1) << 3);
        *(uint2*)(prow + off) = val;
      }

      // PV: acc[df] += P(16q x 64j) * V(64j x 16dh)
      __builtin_amdgcn_s_setprio(1);
      for (int kk = 0; kk < 2; kk++){
        bf16x8 pa = *(const bf16x8*)(prow + ((((kk * 4) + lg) ^ (lr & 7)) << 4));
        for (int df = 0; df < 4; df++){
          bf16x8 bv = *(const bf16x8*)&Vst[df * 16 + lr][((kk * 4 + lg) ^ (lr & 7)) * 8];
          acc[df] = __builtin_amdgcn_mfma_f32_16x16x32_bf16(pa, bv, acc[df], 0, 0, 0);
        }
      }
      __builtin_amdgcn_s_setprio(0);
    }

    // epilogue: divide by l (broadcast to acc-row owners), write attn_vec
    float lb[4];
    for (int r = 0; r < 4; r++) lb[r] = __shfl(l_run, lg * 4 + r, 64);
    for (int df = 0; df < 4; df++){
      for (int r = 0; r < 4; r++){
        int i_glob = q0w + lg * 4 + r;
        AV[((size_t)i_glob * BATCH + b) * DMODEL + n * DHEAD + df * 16 + lr] =
            f2bf(acc[df][r] / lb[r]);
      }
    }
    __syncthreads();
  }
}

// ---------------- LayerNorm: out = g*(xa+xb - mu)*rstd + b ----------------
__global__ __launch_bounds__(256) void ln_kernel(const float* __restrict__ xa,
                                                 const float* __restrict__ xb,
                                                 const float* __restrict__ gamma,
                                                 const float* __restrict__ beta,
                                                 float* __restrict__ outF,
                                                 short* __restrict__ outB){
  __shared__ float red[4];
  const int row = blockIdx.x, t = threadIdx.x;
  const size_t base = (size_t)row * DMODEL + t * 4;
  f32x4 a  = *(const f32x4*)(xa + base);
  f32x4 bb = *(const f32x4*)(xb + base);
  f32x4 x;
  for (int e = 0; e < 4; e++) x[e] = a[e] + bb[e];
  float sum = x[0] + x[1] + x[2] + x[3];
  for (int m = 1; m < 64; m <<= 1) sum += __shfl_xor(sum, m, 64);
  if ((t & 63) == 0) red[t >> 6] = sum;
  __syncthreads();
  float mu = (red[0] + red[1] + red[2] + red[3]) * (1.f / DMODEL);
  float sq = 0.f;
  for (int e = 0; e < 4; e++){ float d = x[e] - mu; sq += d * d; }
  for (int m = 1; m < 64; m <<= 1) sq += __shfl_xor(sq, m, 64);
  __syncthreads();
  if ((t & 63) == 0) red[t >> 6] = sq;
  __syncthreads();
  float var = (red[0] + red[1] + red[2] + red[3]) * (1.f / DMODEL);
  float rstd = rsqrtf(var + 1e-5f);
  f32x4 g  = *(const f32x4*)(gamma + t * 4);
  f32x4 be = *(const f32x4*)(beta + t * 4);
  for (int e = 0; e < 4; e++){
    float y = g[e] * (x[e] - mu) * rstd + be[e];
    if (outF) outF[base + e] = y;
    if (outB) outB[base + e] = f2bf(y);
  }
}

// ---------------- launch ----------------
extern "C" void kernel_launch(void* const* d_in, const int* in_sizes, int n_in,
                              void* d_out, int out_size, void* d_ws, size_t ws_size,
                              hipStream_t stream){
  (void)in_sizes; (void)n_in; (void)out_size; (void)ws_size;
  const float* dec = (const float*)d_in[0];
  const float* qm  = (const float*)d_in[2];
  const float* km  = (const float*)d_in[3];
  const float* vm  = (const float*)d_in[4];
  const float* qs  = (const float*)d_in[5];
  const float* ks  = (const float*)d_in[6];
  const float* vs  = (const float*)d_in[7];
  const float* om  = (const float*)d_in[8];
  const float* os_ = (const float*)d_in[9];
  const float* g1  = (const float*)d_in[10];
  const float* b1  = (const float*)d_in[11];
  const float* w1m = (const float*)d_in[12];
  const float* w2m = (const float*)d_in[13];
  const float* w1s = (const float*)d_in[14];
  const float* w2s = (const float*)d_in[15];
  const float* g2  = (const float*)d_in[16];
  const float* b2  = (const float*)d_in[17];
  float* out = (float*)d_out;

  char* ws = (char*)d_ws;
  size_t off = 0;
  auto alloc = [&](size_t bytes) -> char* {
    char* p = ws + off;
    off += (bytes + 255) & ~(size_t)255;
    return p;
  };
  short* Xb   = (short*)alloc((size_t)MROWS * DMODEL * 2);   // X bf16; then h bf16
  short* Wqkv = (short*)alloc((size_t)QKVN * DMODEL * 2);    // [3072][1024]
  short* W1   = (short*)alloc((size_t)DFF * DMODEL * 2);
  short* W2   = (short*)alloc((size_t)DMODEL * DFF * 2);
  short* Wv   = Wqkv + (size_t)2 * DMODEL * DMODEL;          // V weights within Wqkv
  short* QKVb = (short*)alloc((size_t)MROWS * QKVN * 2);     // [4096][3072], 24MB
  short* AVb  = (short*)alloc((size_t)MROWS * DMODEL * 2);   // 8MB, contiguous after QKVb
  float* tmpF = (float*)alloc((size_t)MROWS * DMODEL * 4);
  float* hF   = (float*)alloc((size_t)MROWS * DMODEL * 4);
  double* acc = (double*)alloc(256);
  short* L1 = QKVb;  // reuse QKVb+AVb region (32MB) for l1 [4096][4096] bf16

  hipMemsetAsync(acc, 0, 16, stream);

  // casts (+ fused KL on the weight tensors)
  cast_kernel<<<MROWS * DMODEL / 1024, 256, 0, stream>>>(dec, Xb, MROWS * DMODEL);
  cast_kl_kernel<<<1024, 256, 0, stream>>>(qm, qs, Wqkv, DMODEL * DMODEL, acc);
  cast_kl_kernel<<<1024, 256, 0, stream>>>(km, ks, Wqkv + (size_t)DMODEL * DMODEL, DMODEL * DMODEL, acc);
  cast_kl_kernel<<<1024, 256, 0, stream>>>(vm, vs, Wqkv + (size_t)2 * DMODEL * DMODEL, DMODEL * DMODEL, acc);
  cast_kl_kernel<<<1024, 256, 0, stream>>>(om, os_, nullptr, DMODEL * DMODEL, acc);
  cast_kl_kernel<<<1024, 256, 0, stream>>>(w1m, w1s, W1, DFF * DMODEL, acc + 1);
  cast_kl_kernel<<<1024, 256, 0, stream>>>(w2m, w2s, W2, DMODEL * DFF, acc + 1);

  // fused QKV projection: [4096][3072] = Xb[4096][1024] @ Wqkv^T
  gemm_bt<128><<<(QKVN / 128) * (MROWS / 128), 512, 0, stream>>>(Xb, Wqkv, nullptr, QKVb, MROWS, QKVN, DMODEL, QKVN / 128);

  // attention (paired q-tiles: uniform 33 K-tiles per block)
  attn_kernel<<<dim3(16, BATCH * NHEADS), 256, 0, stream>>>(QKVb, AVb);

  // attn output projection (bug-faithful: uses value_mean); BN=64 -> 512 blocks
  gemm_bt<64><<<(DMODEL / 64) * (MROWS / 128), 512, 0, stream>>>(AVb, Wv, tmpF, nullptr, MROWS, DMODEL, DMODEL, DMODEL / 64);

  // LN1: h = LN(dec + attn_out) -> hF (f32) + Xb (bf16)
  ln_kernel<<<MROWS, 256, 0, stream>>>(dec, tmpF, g1, b1, hF, Xb);

  // FF
  gemm_bt<128><<<(DFF / 128) * (MROWS / 128), 512, 0, stream>>>(Xb, W1, nullptr, L1, MROWS, DFF, DMODEL, DFF / 128);
  gemm_bt<64><<<(DMODEL / 64) * (MROWS / 128), 512, 0, stream>>>(L1, W2, tmpF, nullptr, MROWS, DMODEL, DFF, DMODEL / 64);

  // LN2 -> final out
  ln_kernel<<<MROWS, 256, 0, stream>>>(hF, tmpF, g2, b2, out, nullptr);

  // KL finalize
  kl_final<<<1, 1, 0, stream>>>(acc, out + (size_t)MROWS * DMODEL);
}

// Round 9
// 479.040 us; speedup vs baseline: 1.1814x; 1.1175x over previous
//
#include <hip/hip_runtime.h>

#define S_LEN  2048
#define BATCH  2
#define DMODEL 1024
#define NHEADS 16
#define DHEAD  64
#define DFF    4096
#define MROWS  (S_LEN*BATCH)   // 4096
#define QKVN   3072

typedef __attribute__((ext_vector_type(8))) short bf16x8;
typedef __attribute__((ext_vector_type(4))) float f32x4;
typedef __attribute__((ext_vector_type(4))) short s16x4;

#define NEG_BIG (-3.0e38f)
#define SCALE_LOG2 (0.125f * 1.4426950408889634f)

__device__ __forceinline__ short f2bf(float f){
  unsigned u = __float_as_uint(f);
  u += 0x7fffu + ((u >> 16) & 1u);
  return (short)(u >> 16);
}
__device__ __forceinline__ float bf2f(short s){
  return __uint_as_float(((unsigned)(unsigned short)s) << 16);
}

__device__ __forceinline__ void gload16(const void* gptr, void* lptr){
  __builtin_amdgcn_global_load_lds(
      (const __attribute__((address_space(1))) unsigned int*)gptr,
      (__attribute__((address_space(3))) unsigned int*)lptr,
      16, 0, 0);
}

// ---------------- cast f32 -> bf16 ----------------
__global__ __launch_bounds__(256) void cast_kernel(const float* __restrict__ in,
                                                   short* __restrict__ out, int n){
  int i = (blockIdx.x * 256 + threadIdx.x) * 4;
  if (i >= n) return;
  f32x4 v = *(const f32x4*)(in + i);
  s16x4 o;
  o[0] = f2bf(v[0]); o[1] = f2bf(v[1]); o[2] = f2bf(v[2]); o[3] = f2bf(v[3]);
  *(s16x4*)(out + i) = o;
}

// ---- fused multi-tensor cast + KL: blockIdx.y selects tensor slot ----------
__global__ __launch_bounds__(256) void cast_kl_multi(
    const float* __restrict__ m0, const float* __restrict__ s0, short* o0,
    const float* __restrict__ m1, const float* __restrict__ s1, short* o1,
    const float* __restrict__ m2, const float* __restrict__ s2, short* o2,
    const float* __restrict__ m3, const float* __restrict__ s3, short* o3,
    int n, double* acc){
  __shared__ double red[4];
  const float* mm; const float* ss; short* oo;
  switch (blockIdx.y){
    case 0: mm = m0; ss = s0; oo = o0; break;
    case 1: mm = m1; ss = s1; oo = o1; break;
    case 2: mm = m2; ss = s2; oo = o2; break;
    default: mm = m3; ss = s3; oo = o3; break;
  }
  if (!mm) return;
  double local = 0.0;
  const int stride = gridDim.x * 1024;
  for (int i = (blockIdx.x * 256 + threadIdx.x) * 4; i < n; i += stride){
    f32x4 m = *(const f32x4*)(mm + i);
    f32x4 sv = *(const f32x4*)(ss + i);
    if (oo){
      s16x4 o;
      o[0] = f2bf(m[0]); o[1] = f2bf(m[1]); o[2] = f2bf(m[2]); o[3] = f2bf(m[3]);
      *(s16x4*)(oo + i) = o;
    }
    for (int e = 0; e < 4; e++)
      local += (double)(m[e] * m[e]) - 2.0 * (double)sv[e] + (double)expf(2.f * sv[e]);
  }
  for (int msk = 1; msk < 64; msk <<= 1) local += __shfl_xor(local, msk, 64);
  const int t = threadIdx.x;
  if ((t & 63) == 0) red[t >> 6] = local;
  __syncthreads();
  if (t == 0) atomicAdd(acc, red[0] + red[1] + red[2] + red[3]);
}

// ---------------- GEMM: C[M][N] = A[M][K] * Bt[N][K]^T ----------------
// 128xBN tile, BK=32, 8 waves, global_load_lds w=16, triple-buffered LDS,
// depth-2 prefetch, counted vmcnt. XCD-L2 mapping: each XCD owns a bx-band
// (B-slice <= 1MB pinned in its 4MB L2), iterates all by (A streams via L3).
// Requires nbx % 8 == 0.
template<int BN>
__global__ __launch_bounds__(512) void gemm_bt(const short* __restrict__ A,
                                               const short* __restrict__ Bt,
                                               float* __restrict__ Cf,
                                               short* __restrict__ Cb,
                                               int M, int N, int K, int nbx){
  __shared__ short As[3][128][32];
  __shared__ short Bs[3][BN][32];
  constexpr int NB = BN / 32;          // n-frags per wave
  constexpr int BSTRIDE = BN * 64;     // bytes per B buffer
  const int t = threadIdx.x;
  const int lane = t & 63, w = t >> 6;
  // XCD-L2 mapping (dispatch round-robins XCDs by blockIdx.x & 7)
  const int bpx = nbx >> 3;
  const int xcd = (int)blockIdx.x & 7;
  const int jj  = (int)blockIdx.x >> 3;
  const int bx = xcd * bpx + (jj % bpx);
  const int by = jj / bpx;
  const int m0 = by * 128, n0 = bx * BN;
  const int wm = (w & 3) * 32, wn = (w >> 2) * (BN / 2);
  const int lr = lane & 15, lg = lane >> 4;
  const bool doB = (BN == 128) || (t < 256);

  f32x4 acc[2][NB] = {};

  const short* Ap = A  + (size_t)(m0 + (t >> 2)) * K + (t & 3) * 8;
  const short* Bp = Bt + (size_t)(n0 + ((t & (BN * 4 - 1)) >> 2)) * K + (t & 3) * 8;
  char* ldsA0 = (char*)As + w * 1024;
  char* ldsB0 = (char*)Bs + (w & (NB * 2 - 1)) * 1024;

  const int nk = K / 32;
  for (int p = 0; p < 2; p++){
    gload16(Ap + p * 32, ldsA0 + p * 8192);
    if (doB) gload16(Bp + p * 32, ldsB0 + p * BSTRIDE);
  }

  int bufcur = 0;
  for (int kt = 0; kt < nk; kt++){
    if (kt + 1 < nk){
      if (doB) asm volatile("s_waitcnt vmcnt(2)" ::: "memory");
      else     asm volatile("s_waitcnt vmcnt(1)" ::: "memory");
    } else {
      asm volatile("s_waitcnt vmcnt(0)" ::: "memory");
    }
    __builtin_amdgcn_s_barrier();
    asm volatile("" ::: "memory");

    if (kt + 2 < nk){
      int bnx = bufcur >= 1 ? bufcur - 1 : bufcur + 2;  // (kt+2)%3
      gload16(Ap + (kt + 2) * 32, ldsA0 + bnx * 8192);
      if (doB) gload16(Bp + (kt + 2) * 32, ldsB0 + bnx * BSTRIDE);
    }

    bf16x8 a0 = *(const bf16x8*)&As[bufcur][wm      + lr][lg * 8];
    bf16x8 a1 = *(const bf16x8*)&As[bufcur][wm + 16 + lr][lg * 8];
    bf16x8 bfr[NB];
    for (int ni = 0; ni < NB; ni++)
      bfr[ni] = *(const bf16x8*)&Bs[bufcur][wn + ni * 16 + lr][lg * 8];
    __builtin_amdgcn_s_setprio(1);
    for (int ni = 0; ni < NB; ni++){
      acc[0][ni] = __builtin_amdgcn_mfma_f32_16x16x32_bf16(a0, bfr[ni], acc[0][ni], 0, 0, 0);
      acc[1][ni] = __builtin_amdgcn_mfma_f32_16x16x32_bf16(a1, bfr[ni], acc[1][ni], 0, 0, 0);
    }
    __builtin_amdgcn_s_setprio(0);
    bufcur = bufcur < 2 ? bufcur + 1 : 0;
  }

  for (int mi = 0; mi < 2; mi++){
    for (int ni = 0; ni < NB; ni++){
      int row = m0 + wm + mi * 16 + lg * 4;
      int col = n0 + wn + ni * 16 + lr;
      for (int r = 0; r < 4; r++){
        float v = acc[mi][ni][r];
        if (Cf) Cf[(size_t)(row + r) * N + col] = v;
        if (Cb) Cb[(size_t)(row + r) * N + col] = f2bf(v);
      }
    }
  }
}

// ---------------- fused causal flash attention (swapped-QK^T, r6-exact) -----
// grid (16, B*NH): each block does q-tiles bx and 31-bx (uniform 33 K-tiles)
__global__ __launch_bounds__(256) void attn_kernel(const short* __restrict__ QKV,
                                                   short* __restrict__ AV){
  __shared__ short Ks[64][64];
  __shared__ short Vst[64][64];   // transposed: [dh][j], swizzled
  __shared__ short Pt[4][16][64]; // per-wave P^T: [q(lr)][j], swizzled
  const int t = threadIdx.x, lane = t & 63, w = t >> 6;
  const int hb = blockIdx.y;
  const int b = hb >> 4, n = hb & 15;
  const int lr = lane & 15, lg = lane >> 4;

  for (int half = 0; half < 2; half++){
    const int qt = half ? (31 - (int)blockIdx.x) : (int)blockIdx.x;
    const int q0w = qt * 64 + w * 16;

    bf16x8 aq[2];
    {
      const short* qp = QKV + ((size_t)(q0w + lr) * BATCH + b) * QKVN + n * DHEAD + lg * 8;
      aq[0] = *(const bf16x8*)(qp);
      aq[1] = *(const bf16x8*)(qp + 32);
    }

    f32x4 acc[4] = {};
    float m_run = NEG_BIG, l_run = 0.f;

    for (int jt = 0; jt <= qt; jt++){
      const int j0 = jt * 64;
      __syncthreads();
      {
        int j = t >> 2, u0 = (t & 3) * 2;
        const short* kp = QKV + ((size_t)(j0 + j) * BATCH + b) * QKVN + DMODEL + n * DHEAD + u0 * 8;
        *(bf16x8*)&Ks[j][(u0 ^ (j & 7)) * 8]       = *(const bf16x8*)(kp);
        *(bf16x8*)&Ks[j][((u0 + 1) ^ (j & 7)) * 8] = *(const bf16x8*)(kp + 8);
        int jv = t & 63, dq = (t >> 6) * 16;
        const short* vp = QKV + ((size_t)(j0 + jv) * BATCH + b) * QKVN + 2 * DMODEL + n * DHEAD + dq;
        bf16x8 v0 = *(const bf16x8*)(vp);
        bf16x8 v1 = *(const bf16x8*)(vp + 8);
        int uj = jv >> 3, jl = jv & 7;
        for (int e = 0; e < 8; e++){
          int sc = (((uj ^ e) << 3) | jl);
          Vst[dq + e][sc]     = v0[e];
          Vst[dq + 8 + e][sc] = v1[e];
        }
      }
      __syncthreads();

      f32x4 s[4];
      __builtin_amdgcn_s_setprio(1);
      for (int nf = 0; nf < 4; nf++){
        f32x4 z = {};
        for (int kk = 0; kk < 2; kk++){
          bf16x8 bk = *(const bf16x8*)&Ks[nf * 16 + lr][((kk * 4 + lg) ^ (lr & 7)) * 8];
          z = __builtin_amdgcn_mfma_f32_16x16x32_bf16(bk, aq[kk], z, 0, 0, 0);
        }
        s[nf] = z;
      }
      __builtin_amdgcn_s_setprio(0);

      for (int nf = 0; nf < 4; nf++)
        for (int r = 0; r < 4; r++) s[nf][r] *= SCALE_LOG2;

      if (jt == qt){
        int qg = q0w + lr;
        for (int nf = 0; nf < 4; nf++)
          for (int r = 0; r < 4; r++)
            if (j0 + nf * 16 + lg * 4 + r > qg) s[nf][r] = NEG_BIG;
      }

      float mx = NEG_BIG;
      for (int nf = 0; nf < 4; nf++){
        float a0 = fmaxf(s[nf][0], s[nf][1]);
        float a1 = fmaxf(s[nf][2], s[nf][3]);
        mx = fmaxf(mx, fmaxf(a0, a1));
      }
      mx = fmaxf(mx, __shfl_xor(mx, 16, 64));
      mx = fmaxf(mx, __shfl_xor(mx, 32, 64));
      float mn = fmaxf(m_run, mx);
      float corr = __builtin_exp2f(m_run - mn);
      m_run = mn;

      float rs = 0.f;
      for (int nf = 0; nf < 4; nf++)
        for (int r = 0; r < 4; r++){
          float p = __builtin_exp2f(s[nf][r] - mn);
          s[nf][r] = p;
          rs += p;
        }
      rs += __shfl_xor(rs, 16, 64);
      rs += __shfl_xor(rs, 32, 64);
      l_run = l_run * corr + rs;

      char* prow = (char*)&Pt[w][lr][0];
      for (int nf = 0; nf < 4; nf++){
        unsigned u0 = __float_as_uint(s[nf][0]);
        unsigned u1 = __float_as_uint(s[nf][1]);
        unsigned u2 = __float_as_uint(s[nf][2]);
        unsigned u3 = __float_as_uint(s[nf][3]);
        uint2 val;
        val.x = (u0 >> 16) | (u1 & 0xffff0000u);
        val.y = (u2 >> 16) | (u3 & 0xffff0000u);
        int off = ((((nf * 2) + (lg >> 1)) ^ (lr & 7)) << 4) + ((lg & 1) << 3);
        *(uint2*)(prow + off) = val;
      }

      float cb[4];
      for (int r = 0; r < 4; r++) cb[r] = __shfl(corr, lg * 4 + r, 64);
      for (int df = 0; df < 4; df++)
        for (int r = 0; r < 4; r++) acc[df][r] *= cb[r];

      __builtin_amdgcn_s_setprio(1);
      for (int kk = 0; kk < 2; kk++){
        bf16x8 pa = *(const bf16x8*)(prow + ((((kk * 4) + lg) ^ (lr & 7)) << 4));
        for (int df = 0; df < 4; df++){
          bf16x8 bv = *(const bf16x8*)&Vst[df * 16 + lr][((kk * 4 + lg) ^ (lr & 7)) * 8];
          acc[df] = __builtin_amdgcn_mfma_f32_16x16x32_bf16(pa, bv, acc[df], 0, 0, 0);
        }
      }
      __builtin_amdgcn_s_setprio(0);
    }

    float lb[4];
    for (int r = 0; r < 4; r++) lb[r] = __shfl(l_run, lg * 4 + r, 64);
    for (int df = 0; df < 4; df++){
      for (int r = 0; r < 4; r++){
        int i_glob = q0w + lg * 4 + r;
        AV[((size_t)i_glob * BATCH + b) * DMODEL + n * DHEAD + df * 16 + lr] =
            f2bf(acc[df][r] / lb[r]);
      }
    }
    __syncthreads();
  }
}

// -------- LayerNorm: out = g*(xa + bf2f(xbB) - mu)*rstd + b; optional KL ----
__global__ __launch_bounds__(256) void ln_kernel(const float* __restrict__ xa,
                                                 const short* __restrict__ xbB,
                                                 const float* __restrict__ gamma,
                                                 const float* __restrict__ beta,
                                                 float* __restrict__ outF,
                                                 short* __restrict__ outB,
                                                 const double* __restrict__ klacc,
                                                 float* __restrict__ klout){
  __shared__ float red[4];
  const int row = blockIdx.x, t = threadIdx.x;
  const size_t base = (size_t)row * DMODEL + t * 4;
  f32x4 a  = *(const f32x4*)(xa + base);
  s16x4 bb = *(const s16x4*)(xbB + base);
  f32x4 x;
  for (int e = 0; e < 4; e++) x[e] = a[e] + bf2f(bb[e]);
  float sum = x[0] + x[1] + x[2] + x[3];
  for (int m = 1; m < 64; m <<= 1) sum += __shfl_xor(sum, m, 64);
  if ((t & 63) == 0) red[t >> 6] = sum;
  __syncthreads();
  float mu = (red[0] + red[1] + red[2] + red[3]) * (1.f / DMODEL);
  float sq = 0.f;
  for (int e = 0; e < 4; e++){ float d = x[e] - mu; sq += d * d; }
  for (int m = 1; m < 64; m <<= 1) sq += __shfl_xor(sq, m, 64);
  __syncthreads();
  if ((t & 63) == 0) red[t >> 6] = sq;
  __syncthreads();
  float var = (red[0] + red[1] + red[2] + red[3]) * (1.f / DMODEL);
  float rstd = rsqrtf(var + 1e-5f);
  f32x4 g  = *(const f32x4*)(gamma + t * 4);
  f32x4 be = *(const f32x4*)(beta + t * 4);
  for (int e = 0; e < 4; e++){
    float y = g[e] * (x[e] - mu) * rstd + be[e];
    if (outF) outF[base + e] = y;
    if (outB) outB[base + e] = f2bf(y);
  }
  if (klout && row == 0 && t == 0)
    klout[0] = (float)(klacc[0] / 8388608.0 + klacc[1] / 16777216.0);
}

// ---------------- launch ----------------
extern "C" void kernel_launch(void* const* d_in, const int* in_sizes, int n_in,
                              void* d_out, int out_size, void* d_ws, size_t ws_size,
                              hipStream_t stream){
  (void)in_sizes; (void)n_in; (void)out_size; (void)ws_size;
  const float* dec = (const float*)d_in[0];
  const float* qm  = (const float*)d_in[2];
  const float* km  = (const float*)d_in[3];
  const float* vm  = (const float*)d_in[4];
  const float* qs  = (const float*)d_in[5];
  const float* ks  = (const float*)d_in[6];
  const float* vs  = (const float*)d_in[7];
  const float* om  = (const float*)d_in[8];
  const float* os_ = (const float*)d_in[9];
  const float* g1  = (const float*)d_in[10];
  const float* b1  = (const float*)d_in[11];
  const float* w1m = (const float*)d_in[12];
  const float* w2m = (const float*)d_in[13];
  const float* w1s = (const float*)d_in[14];
  const float* w2s = (const float*)d_in[15];
  const float* g2  = (const float*)d_in[16];
  const float* b2  = (const float*)d_in[17];
  float* out = (float*)d_out;

  char* ws = (char*)d_ws;
  size_t off = 0;
  auto alloc = [&](size_t bytes) -> char* {
    char* p = ws + off;
    off += (bytes + 255) & ~(size_t)255;
    return p;
  };
  short* Xb   = (short*)alloc((size_t)MROWS * DMODEL * 2);   // X bf16; then h bf16
  short* Wqkv = (short*)alloc((size_t)QKVN * DMODEL * 2);    // [3072][1024]
  short* W1   = (short*)alloc((size_t)DFF * DMODEL * 2);
  short* W2   = (short*)alloc((size_t)DMODEL * DFF * 2);
  short* Wv   = Wqkv + (size_t)2 * DMODEL * DMODEL;          // V weights within Wqkv
  short* QKVb = (short*)alloc((size_t)MROWS * QKVN * 2);     // 24MB
  short* AVb  = (short*)alloc((size_t)MROWS * DMODEL * 2);   // 8MB (contig after QKVb)
  short* tmpB = (short*)alloc((size_t)MROWS * DMODEL * 2);   // bf16 residual branch
  float* hF   = (float*)alloc((size_t)MROWS * DMODEL * 4);
  double* acc = (double*)alloc(256);
  short* L1 = QKVb;  // reuse QKVb+AVb (32MB) for l1 [4096][4096] bf16

  hipMemsetAsync(acc, 0, 16, stream);

  cast_kernel<<<MROWS * DMODEL / 1024, 256, 0, stream>>>(dec, Xb, MROWS * DMODEL);
  cast_kl_multi<<<dim3(256, 4), 256, 0, stream>>>(
      qm, qs, Wqkv,
      km, ks, Wqkv + (size_t)DMODEL * DMODEL,
      vm, vs, Wqkv + (size_t)2 * DMODEL * DMODEL,
      om, os_, nullptr,
      DMODEL * DMODEL, acc);
  cast_kl_multi<<<dim3(512, 2), 256, 0, stream>>>(
      w1m, w1s, W1,
      w2m, w2s, W2,
      nullptr, nullptr, nullptr,
      nullptr, nullptr, nullptr,
      DFF * DMODEL, acc + 1);

  // fused QKV projection
  gemm_bt<128><<<(QKVN / 128) * (MROWS / 128), 512, 0, stream>>>(Xb, Wqkv, nullptr, QKVb, MROWS, QKVN, DMODEL, QKVN / 128);

  // attention (paired q-tiles)
  attn_kernel<<<dim3(16, BATCH * NHEADS), 256, 0, stream>>>(QKVb, AVb);

  // attn output projection (bug-faithful: value_mean) -> bf16
  gemm_bt<64><<<(DMODEL / 64) * (MROWS / 128), 512, 0, stream>>>(AVb, Wv, nullptr, tmpB, MROWS, DMODEL, DMODEL, DMODEL / 64);

  // LN1: h = LN(dec + attn_out) -> hF (f32) + Xb (bf16)
  ln_kernel<<<MROWS, 256, 0, stream>>>(dec, tmpB, g1, b1, hF, Xb, nullptr, nullptr);

  // FF
  gemm_bt<128><<<(DFF / 128) * (MROWS / 128), 512, 0, stream>>>(Xb, W1, nullptr, L1, MROWS, DFF, DMODEL, DFF / 128);
  gemm_bt<64><<<(DMODEL / 64) * (MROWS / 128), 512, 0, stream>>>(L1, W2, nullptr, tmpB, MROWS, DMODEL, DFF, DMODEL / 64);

  // LN2 -> final out (+ fused KL finalize)
  ln_kernel<<<MROWS, 256, 0, stream>>>(hF, tmpB, g2, b2, out, nullptr, acc, out + (size_t)MROWS * DMODEL);
}